// Round 17
// baseline (214.152 us; speedup 1.0000x reference)
//
#include <hip/hip_runtime.h>

#define BATCH 65536
#define DIM 128
#define NPROTO 512
#define ODIM 8

#define ROWS 128           // rows per block; lane covers rows (lane) and (lane+64)
#define THREADS 512        // 8 waves
#define CHUNK 128          // protos per LDS w-chunk (4 chunks); wave takes 16/chunk

// wTg layout: float4 index [c][p]  (c = dim/4 in [0,32), p in [0,512)) -> 256 KB

// ---------------- prep_w: thread = (c, p): p fastest -> coalesced writes to wTg
__global__ void grlvq_prep_w(const float* __restrict__ proto,
                             const float* __restrict__ rel,
                             float* __restrict__ wTg) {
    const int tid = blockIdx.x * 256 + threadIdx.x;   // 0..16383
    const int c = tid >> 9, p = tid & 511;
    float4 rv = *(const float4*)(rel + c * 4);
    float4 pv = *(const float4*)(proto + (size_t)p * DIM + c * 4);
    float4 o;
    o.x = pv.x * (rv.x * rv.x);
    o.y = pv.y * (rv.y * rv.y);
    o.z = pv.z * (rv.z * rv.z);
    o.w = pv.w * (rv.w * rv.w);
    ((float4*)wTg)[c * 512 + p] = o;
}

// ---------------- prep_psq: serial per-proto chain, exact fmaf order (bitwise-stable)
__global__ void grlvq_prep_psq(const float* __restrict__ proto,
                               const float* __restrict__ rel,
                               float* __restrict__ psq) {
    const int p = blockIdx.x * 64 + threadIdx.x;
    float acc = 0.f;
    #pragma unroll 8
    for (int c = 0; c < 32; ++c) {
        float4 rv = *(const float4*)(rel + c * 4);
        float4 pv = *(const float4*)(proto + (size_t)p * DIM + c * 4);
        float r2;
        r2 = rv.x * rv.x; acc = fmaf(r2 * pv.x, pv.x, acc);
        r2 = rv.y * rv.y; acc = fmaf(r2 * pv.y, pv.y, acc);
        r2 = rv.z * rv.z; acc = fmaf(r2 * pv.z, pv.z, acc);
        r2 = rv.w * rv.w; acc = fmaf(r2 * pv.w, pv.w, acc);
    }
    psq[p] = acc;
}

// ---------------- fused main: x-tile AND w-chunk both in LDS.
// w reads are wave-uniform ds_read_b128 broadcasts (short-latency, deeply
// pipelined) replacing K$-missing s_loads — that latency was R15's 37% stall.
__global__ __launch_bounds__(THREADS, 1) void grlvq_main(const float* __restrict__ x,
                                                         const float* __restrict__ wTg,
                                                         const float* __restrict__ psq,
                                                         const float* __restrict__ pout,
                                                         float* __restrict__ out) {
    __shared__ __align__(16) float4 xs4[32 * 128];   // 64 KB  [c][r]
    __shared__ __align__(16) float4 ws4[32 * CHUNK]; // 64 KB  [c][p_local]
    __shared__ float red_s[ROWS * 8];                // 4 KB
    __shared__ int   red_i[ROWS * 8];                // 4 KB   => 136 KB total

    const int t = threadIdx.x;
    const int rowBase = blockIdx.x * ROWS;

    // stage x: thread (r = t&127, cbase = t>>7) loads c = cbase+4k, k=0..7
    {
        const int r = t & 127;
        const int cbase = t >> 7;
        const float4* xg = (const float4*)(x + (size_t)(rowBase + r) * DIM);
        #pragma unroll
        for (int k = 0; k < 8; ++k) {
            const int c = cbase + 4 * k;
            xs4[c * 128 + r] = xg[c];
        }
    }

    const int lane = t & 63;
    const int wid  = __builtin_amdgcn_readfirstlane(t >> 6);
    const float4* wTg4 = (const float4*)wTg;

    float bestA = INFINITY, bestB = INFINITY;
    int idxA = 0, idxB = 0;

    #pragma unroll 1
    for (int ch = 0; ch < NPROTO / CHUNK; ++ch) {
        __syncthreads();   // (a) x ready on first pass; (b) previous chunk's readers done
        // stage w-chunk: 32c x 128p float4s; thread stages 8, coalesced in p
        #pragma unroll
        for (int k = 0; k < 8; ++k) {
            const int idx = t + k * THREADS;        // 0..4095
            const int c = idx >> 7, pl = idx & 127;
            ws4[c * 128 + pl] = wTg4[c * 512 + ch * CHUNK + pl];
        }
        __syncthreads();

        float accA[16], accB[16];
        #pragma unroll
        for (int j = 0; j < 16; ++j) { accA[j] = 0.f; accB[j] = 0.f; }

        #pragma unroll 4
        for (int c = 0; c < 32; ++c) {
            float4 xa = xs4[c * 128 + lane];          // per-lane, 2-way (free)
            float4 xb = xs4[c * 128 + lane + 64];
            const float4* wrow = &ws4[c * 128 + wid * 16];   // uniform -> broadcast
            #pragma unroll
            for (int j = 0; j < 16; ++j) {
                float4 wv = wrow[j];
                accA[j] = fmaf(xa.x, wv.x, accA[j]);
                accA[j] = fmaf(xa.y, wv.y, accA[j]);
                accA[j] = fmaf(xa.z, wv.z, accA[j]);
                accA[j] = fmaf(xa.w, wv.w, accA[j]);
                accB[j] = fmaf(xb.x, wv.x, accB[j]);
                accB[j] = fmaf(xb.y, wv.y, accB[j]);
                accB[j] = fmaf(xb.z, wv.z, accB[j]);
                accB[j] = fmaf(xb.w, wv.w, accB[j]);
            }
        }

        #pragma unroll
        for (int j = 0; j < 16; ++j) {   // ascending j = ascending global proto within wave
            const int p = ch * CHUNK + wid * 16 + j;
            float pq = psq[p];
            float sA = pq - 2.0f * accA[j];
            float sB = pq - 2.0f * accB[j];
            if (sA < bestA) { bestA = sA; idxA = p; }
            if (sB < bestB) { bestB = sB; idxB = p; }
        }
    }

    __syncthreads();
    red_s[lane * 8 + wid] = bestA;        red_i[lane * 8 + wid] = idxA;
    red_s[(lane + 64) * 8 + wid] = bestB; red_i[(lane + 64) * 8 + wid] = idxB;
    __syncthreads();

    if (t < ROWS) {
        float b = INFINITY;
        int bi = 0x7fffffff;
        #pragma unroll
        for (int w8 = 0; w8 < 8; ++w8) {
            float s = red_s[t * 8 + w8];
            int  id = red_i[t * 8 + w8];
            // wave proto-sets interleave -> explicit first-min tie-break on index
            if (s < b || (s == b && id < bi)) { b = s; bi = id; }
        }
        const float4* po = (const float4*)(pout + (size_t)bi * ODIM);
        float4* op = (float4*)(out + (size_t)(rowBase + t) * ODIM);
        op[0] = po[0];
        op[1] = po[1];
    }
}

extern "C" void kernel_launch(void* const* d_in, const int* in_sizes, int n_in,
                              void* d_out, int out_size, void* d_ws, size_t ws_size,
                              hipStream_t stream) {
    const float* x     = (const float*)d_in[0];  // [BATCH, DIM]
    const float* proto = (const float*)d_in[1];  // [NPROTO, DIM]
    const float* pout  = (const float*)d_in[2];  // [NPROTO, ODIM]
    const float* rel   = (const float*)d_in[3];  // [DIM]
    float* out = (float*)d_out;                  // [BATCH, ODIM]

    float* wTg = (float*)d_ws;                   // NPROTO*DIM floats (256 KB), [c][p] float4
    float* psq = wTg + NPROTO * DIM;             // NPROTO floats

    grlvq_prep_w<<<64, 256, 0, stream>>>(proto, rel, wTg);
    grlvq_prep_psq<<<8, 64, 0, stream>>>(proto, rel, psq);
    grlvq_main<<<BATCH / ROWS, THREADS, 0, stream>>>(x, wTg, psq, pout, out);
}